// Round 1
// baseline (464.694 us; speedup 1.0000x reference)
//
#include <hip/hip_runtime.h>
#include <stdint.h>

typedef float f32x4 __attribute__((ext_vector_type(4)));
typedef short s16x8 __attribute__((ext_vector_type(8)));

#define EDIM 64
#define HID 128
#define NG 128
#define NC 10

static __device__ __forceinline__ unsigned short f2bf(float x) {
  unsigned int u = __float_as_uint(x);
  u += 0x7FFFu + ((u >> 16) & 1u);   // round-to-nearest-even
  return (unsigned short)(u >> 16);
}
static __device__ __forceinline__ unsigned int encf(float f) {
  unsigned int u = __float_as_uint(f);
  return (u & 0x80000000u) ? ~u : (u | 0x80000000u);  // monotonic order-preserving map
}
static __device__ __forceinline__ float decf(unsigned int u) {
  unsigned int b = (u & 0x80000000u) ? (u & 0x7FFFFFFFu) : ~u;
  return __uint_as_float(b);
}

// ---------------- pack weights: f32 [K][N] -> bf16 transposed+swizzled [N][K] ----------------
__global__ void pack_w_kernel(const float* __restrict__ W1, const float* __restrict__ W2,
                              const float* __restrict__ W3, unsigned short* __restrict__ wt1,
                              unsigned short* __restrict__ wt2, unsigned short* __restrict__ wt3) {
  int gid = blockIdx.x * 256 + threadIdx.x;  // 40960 total
  if (gid < 8192) {                           // W1: K=64, N=128
    int k = gid >> 7, n = gid & 127;
    int off = (n * 128 + k * 2) ^ ((n & 7) << 4);
    *(unsigned short*)((char*)wt1 + off) = f2bf(W1[k * 128 + n]);
  } else if (gid < 24576) {                   // W2: K=128
    int idx = gid - 8192; int k = idx >> 7, n = idx & 127;
    int off = (n * 256 + k * 2) ^ ((n & 7) << 4);
    *(unsigned short*)((char*)wt2 + off) = f2bf(W2[k * 128 + n]);
  } else if (gid < 40960) {                   // W3: K=128
    int idx = gid - 24576; int k = idx >> 7, n = idx & 127;
    int off = (n * 256 + k * 2) ^ ((n & 7) << 4);
    *(unsigned short*)((char*)wt3 + off) = f2bf(W3[k * 128 + n]);
  }
}

// ---------------- h_self = MLP(0) (f32, exact) ----------------
__global__ void hself_kernel(const float* __restrict__ b1, const float* __restrict__ W2,
                             const float* __restrict__ b2, const float* __restrict__ W3,
                             const float* __restrict__ b3, unsigned int* __restrict__ hself_enc) {
  __shared__ float s1[HID], s2[HID];
  int t = threadIdx.x;  // 128
  float h1 = b1[t]; h1 = h1 > 0.f ? h1 : 0.f; s1[t] = h1;
  __syncthreads();
  float h2 = b2[t];
  for (int k = 0; k < HID; ++k) h2 += s1[k] * W2[k * HID + t];
  h2 = h2 > 0.f ? h2 : 0.f; s2[t] = h2;
  __syncthreads();
  float h3 = b3[t];
  for (int k = 0; k < HID; ++k) h3 += s2[k] * W3[k * HID + t];
  hself_enc[t] = encf(h3);
}

// ---------------- init node array with enc(h_self), zero pool sums/counts ----------------
__global__ void init_kernel(unsigned int* __restrict__ node_enc,
                            const unsigned int* __restrict__ hself_enc,
                            float* __restrict__ pool0, int total_node) {
  int i = blockIdx.x * 256 + threadIdx.x;
  if (i < total_node) {
    node_enc[i] = hself_enc[i & 127];
  } else {
    int j = i - total_node;
    if (j < NG * HID + NG) pool0[j] = 0.f;
  }
}

// ---------------- fused edge MLP + scatter-max ----------------
__global__ __launch_bounds__(256, 3) void edge_kernel(
    const float* __restrict__ edge_attr, const int* __restrict__ dst,
    const unsigned short* __restrict__ wt1, const unsigned short* __restrict__ wt2,
    const unsigned short* __restrict__ wt3, unsigned int* __restrict__ node_enc, int E) {
  __shared__ __align__(16) unsigned short Wbuf[16384];   // 32 KB, restaged per layer
  __shared__ __align__(16) unsigned short hbuf[64 * 128]; // 16 KB, swizzled
  __shared__ int sdst[64];

  const int tid = threadIdx.x;
  const int w = tid >> 6;        // wave 0..3, owns rows w*16..w*16+15
  const int l = tid & 63;
  const int l4 = l >> 4;         // 0..3
  const int lm = l & 15;         // 0..15
  const int e0 = blockIdx.x * 64;

  if (tid < 64) { int e = e0 + tid; sdst[tid] = (e < E) ? dst[e] : 0; }

  { // stage W1T (16 KB)
    const uint4* s = (const uint4*)wt1; uint4* d = (uint4*)Wbuf;
    #pragma unroll
    for (int i = 0; i < 4; ++i) d[tid + i * 256] = s[tid + i * 256];
  }

  // layer-1 A fragments straight from global (f32 -> bf16)
  int arow = e0 + w * 16 + lm; if (arow >= E) arow = E - 1;
  const float* ap = edge_attr + (size_t)arow * EDIM + l4 * 8;
  s16x8 a1[2];
  #pragma unroll
  for (int kf = 0; kf < 2; ++kf) {
    f32x4 x0 = *(const f32x4*)(ap + kf * 32);
    f32x4 x1 = *(const f32x4*)(ap + kf * 32 + 4);
    s16x8 a;
    a[0] = (short)f2bf(x0[0]); a[1] = (short)f2bf(x0[1]);
    a[2] = (short)f2bf(x0[2]); a[3] = (short)f2bf(x0[3]);
    a[4] = (short)f2bf(x1[0]); a[5] = (short)f2bf(x1[1]);
    a[6] = (short)f2bf(x1[2]); a[7] = (short)f2bf(x1[3]);
    a1[kf] = a;
  }
  __syncthreads();  // B0: Wbuf=W1 ready, sdst ready

  f32x4 acc[8];
  #pragma unroll
  for (int nf = 0; nf < 8; ++nf) acc[nf] = (f32x4){0.f, 0.f, 0.f, 0.f};

  // ---- layer 1: [64x64] @ [64x128] ----
  #pragma unroll
  for (int kf = 0; kf < 2; ++kf) {
    #pragma unroll
    for (int nf = 0; nf < 8; ++nf) {
      int n = nf * 16 + lm;
      int off = (n * 128 + kf * 64 + l4 * 16) ^ ((n & 7) << 4);
      s16x8 b = *(const s16x8*)((const char*)Wbuf + off);
      acc[nf] = __builtin_amdgcn_mfma_f32_16x16x32_bf16(a1[kf], b, acc[nf], 0, 0, 0);
    }
  }

  // write h1 (relu) — intra-wave relayout through LDS
  #pragma unroll
  for (int nf = 0; nf < 8; ++nf) {
    #pragma unroll
    for (int i = 0; i < 4; ++i) {
      int rl = w * 16 + l4 * 4 + i;
      int c = nf * 16 + lm;
      float v = acc[nf][i]; v = v > 0.f ? v : 0.f;
      int off = (rl * 256 + c * 2) ^ ((rl & 7) << 4);
      *(unsigned short*)((char*)hbuf + off) = f2bf(v);
    }
  }
  __syncthreads();  // B1: all waves done reading Wbuf(W1)

  { // stage W2T (32 KB)
    const uint4* s = (const uint4*)wt2; uint4* d = (uint4*)Wbuf;
    #pragma unroll
    for (int i = 0; i < 8; ++i) d[tid + i * 256] = s[tid + i * 256];
  }
  __syncthreads();  // B2: Wbuf=W2 ready

  // ---- layer 2: [64x128] @ [128x128] ----
  #pragma unroll
  for (int nf = 0; nf < 8; ++nf) acc[nf] = (f32x4){0.f, 0.f, 0.f, 0.f};
  #pragma unroll
  for (int kf = 0; kf < 4; ++kf) {
    int ar = w * 16 + lm;
    int aoff = (ar * 256 + kf * 64 + l4 * 16) ^ ((ar & 7) << 4);
    s16x8 a = *(const s16x8*)((const char*)hbuf + aoff);
    #pragma unroll
    for (int nf = 0; nf < 8; ++nf) {
      int n = nf * 16 + lm;
      int off = (n * 256 + kf * 64 + l4 * 16) ^ ((n & 7) << 4);
      s16x8 b = *(const s16x8*)((const char*)Wbuf + off);
      acc[nf] = __builtin_amdgcn_mfma_f32_16x16x32_bf16(a, b, acc[nf], 0, 0, 0);
    }
  }

  // write h2 (relu)
  #pragma unroll
  for (int nf = 0; nf < 8; ++nf) {
    #pragma unroll
    for (int i = 0; i < 4; ++i) {
      int rl = w * 16 + l4 * 4 + i;
      int c = nf * 16 + lm;
      float v = acc[nf][i]; v = v > 0.f ? v : 0.f;
      int off = (rl * 256 + c * 2) ^ ((rl & 7) << 4);
      *(unsigned short*)((char*)hbuf + off) = f2bf(v);
    }
  }
  __syncthreads();  // B3: all waves done reading Wbuf(W2)

  { // stage W3T (32 KB)
    const uint4* s = (const uint4*)wt3; uint4* d = (uint4*)Wbuf;
    #pragma unroll
    for (int i = 0; i < 8; ++i) d[tid + i * 256] = s[tid + i * 256];
  }
  __syncthreads();  // B4: Wbuf=W3 ready

  // ---- layer 3: [64x128] @ [128x128], no relu ----
  #pragma unroll
  for (int nf = 0; nf < 8; ++nf) acc[nf] = (f32x4){0.f, 0.f, 0.f, 0.f};
  #pragma unroll
  for (int kf = 0; kf < 4; ++kf) {
    int ar = w * 16 + lm;
    int aoff = (ar * 256 + kf * 64 + l4 * 16) ^ ((ar & 7) << 4);
    s16x8 a = *(const s16x8*)((const char*)hbuf + aoff);
    #pragma unroll
    for (int nf = 0; nf < 8; ++nf) {
      int n = nf * 16 + lm;
      int off = (n * 256 + kf * 64 + l4 * 16) ^ ((n & 7) << 4);
      s16x8 b = *(const s16x8*)((const char*)Wbuf + off);
      acc[nf] = __builtin_amdgcn_mfma_f32_16x16x32_bf16(a, b, acc[nf], 0, 0, 0);
    }
  }

  // scatter-max directly from accumulator fragments
  #pragma unroll
  for (int nf = 0; nf < 8; ++nf) {
    #pragma unroll
    for (int i = 0; i < 4; ++i) {
      int rl = l4 * 4 + i;                 // local row 0..15
      int ge = e0 + w * 16 + rl;
      if (ge < E) {
        int d = sdst[w * 16 + rl];
        unsigned int u = encf(acc[nf][i]);
        unsigned int* p = node_enc + (size_t)d * HID + nf * 16 + lm;
        unsigned int old = *p;             // stale is always <= current: safe pre-test
        if (u > old) atomicMax(p, u);
      }
    }
  }
}

// ---------------- mean pool (batch is sorted) ----------------
__global__ void pool_kernel(const unsigned int* __restrict__ node_enc,
                            const int* __restrict__ batch, float* __restrict__ sums,
                            float* __restrict__ counts, int N) {
  __shared__ int sb[128];
  int t = threadIdx.x;  // 128
  int b0 = blockIdx.x * 128;
  sb[t] = (b0 + t < N) ? batch[b0 + t] : -1;
  __syncthreads();
  int nmax = N - b0; if (nmax > 128) nmax = 128;
  if (nmax <= 0) return;
  float acc = 0.f; int cur = sb[0]; int cnt = 0;
  for (int j = 0; j < nmax; ++j) {
    int g = sb[j];
    if (g != cur) {
      atomicAdd(&sums[cur * HID + t], acc);
      if (t == 0) atomicAdd(&counts[cur], (float)cnt);
      acc = 0.f; cnt = 0; cur = g;
    }
    acc += decf(node_enc[(size_t)(b0 + j) * HID + t]);
    cnt++;
  }
  atomicAdd(&sums[cur * HID + t], acc);
  if (t == 0) atomicAdd(&counts[cur], (float)cnt);
}

// ---------------- classifier ----------------
__global__ void cls_kernel(const float* __restrict__ sums, const float* __restrict__ counts,
                           const float* __restrict__ Wc1, const float* __restrict__ bc1,
                           const float* __restrict__ Wc2, const float* __restrict__ bc2,
                           float* __restrict__ out) {
  __shared__ float sg[HID], sh[HID];
  int g = blockIdx.x, t = threadIdx.x;  // 128 threads
  float c = counts[g]; c = c > 1.f ? c : 1.f;
  sg[t] = sums[g * HID + t] / c;
  __syncthreads();
  float a = bc1[t];
  #pragma unroll 8
  for (int k = 0; k < HID; ++k) a += sg[k] * Wc1[k * HID + t];
  sh[t] = a > 0.f ? a : 0.f;
  __syncthreads();
  if (t < NC) {
    float o = bc2[t];
    #pragma unroll 8
    for (int h = 0; h < HID; ++h) o += sh[h] * Wc2[h * NC + t];
    out[g * NC + t] = o;
  }
}

extern "C" void kernel_launch(void* const* d_in, const int* in_sizes, int n_in,
                              void* d_out, int out_size, void* d_ws, size_t ws_size,
                              hipStream_t stream) {
  const float* edge_attr = (const float*)d_in[0];
  const float* W1 = (const float*)d_in[1];
  const float* b1 = (const float*)d_in[2];
  const float* W2 = (const float*)d_in[3];
  const float* b2 = (const float*)d_in[4];
  const float* W3 = (const float*)d_in[5];
  const float* b3 = (const float*)d_in[6];
  const float* Wc1 = (const float*)d_in[7];
  const float* bc1 = (const float*)d_in[8];
  const float* Wc2 = (const float*)d_in[9];
  const float* bc2 = (const float*)d_in[10];
  const int* ei = (const int*)d_in[11];
  const int* batch = (const int*)d_in[12];

  const int E = in_sizes[0] / EDIM;
  const int N = in_sizes[12];

  char* ws = (char*)d_ws;
  unsigned int* node_enc = (unsigned int*)ws;                       // N*128 u32
  float* sums = (float*)(ws + (size_t)N * HID * 4);                 // 128*128 f32
  float* counts = sums + NG * HID;                                  // 128 f32
  unsigned int* hself_enc = (unsigned int*)(counts + NG);           // 128 u32
  unsigned short* wt1 = (unsigned short*)(hself_enc + HID);         // 8192 bf16
  unsigned short* wt2 = wt1 + 8192;                                 // 16384 bf16
  unsigned short* wt3 = wt2 + 16384;                                // 16384 bf16

  pack_w_kernel<<<160, 256, 0, stream>>>(W1, W2, W3, wt1, wt2, wt3);
  hself_kernel<<<1, 128, 0, stream>>>(b1, W2, b2, W3, b3, hself_enc);

  int total_node = N * HID;
  int init_elems = total_node + NG * HID + NG;
  init_kernel<<<(init_elems + 255) / 256, 256, 0, stream>>>(node_enc, hself_enc, sums, total_node);

  edge_kernel<<<(E + 63) / 64, 256, 0, stream>>>(edge_attr, ei + E, wt1, wt2, wt3, node_enc, E);

  pool_kernel<<<(N + 127) / 128, 128, 0, stream>>>(node_enc, batch, sums, counts, N);
  cls_kernel<<<NG, 128, 0, stream>>>(sums, counts, Wc1, bc1, Wc2, bc2, (float*)d_out);
}